// Round 4
// baseline (2376.703 us; speedup 1.0000x reference)
//
#include <hip/hip_runtime.h>
#include <hip/hip_bf16.h>
#include <math.h>

#define B_ 8
#define L_ 512
#define DV_ 512
#define DM_ 512
#define PL_ 96
#define EL_ 3
#define DS_ 16
#define DC_ 4
#define DI_ 1024
#define DTR_ 32
#define S_ 512
#define CH_ 16         // scan chunks
#define CS_ 32         // steps per chunk

typedef float f32x4 __attribute__((ext_vector_type(4)));
typedef short bf16x8 __attribute__((ext_vector_type(8)));

__device__ __forceinline__ float bf2f(short s) {
  unsigned u = ((unsigned)(unsigned short)s) << 16;
  return __builtin_bit_cast(float, u);
}
__device__ __forceinline__ short f2bf(float f) {
  unsigned u = __builtin_bit_cast(unsigned, f);
  u = u + 0x7FFFu + ((u >> 16) & 1u);   // RNE
  return (short)(u >> 16);
}
__device__ __forceinline__ float h2f(unsigned short u) {
  _Float16 h = __builtin_bit_cast(_Float16, u);
  return (float)h;
}
__device__ __forceinline__ unsigned short f2h(float f) {
  _Float16 h = (_Float16)f;
  return __builtin_bit_cast(unsigned short, h);
}

// async global->LDS, 16B per lane; lds dest must be wave-uniform base.
__device__ __forceinline__ void load_lds16(const short* g, short* l) {
  __builtin_amdgcn_global_load_lds(
      (const __attribute__((address_space(1))) void*)g,
      (__attribute__((address_space(3))) void*)l, 16, 0, 0);
}

// ---------------------------------------------------------------------------
// Instance-norm statistics over the time axis (L) of x (B,L,DV) fp32.
// ---------------------------------------------------------------------------
__global__ __launch_bounds__(256)
void stats_k(const float* __restrict__ x, float* __restrict__ means,
             float* __restrict__ stdev, float* __restrict__ rstd,
             float* __restrict__ xlast)
{
  int d = blockIdx.x * 256 + threadIdx.x;       // 0..511
  int b = blockIdx.y;
  const float* xp = x + (size_t)b * L_ * DV_ + d;
  float s = 0.f, ss = 0.f;
  for (int l = 0; l < L_; l++) {
    float v = xp[(size_t)l * DV_];
    s += v; ss += v * v;
  }
  float mu = s / (float)L_;
  float var = ss / (float)L_ - mu * mu;
  float sd = sqrtf(var + 1e-5f);
  float rs = 1.f / sd;
  int idx = b * DV_ + d;
  means[idx] = mu; stdev[idx] = sd; rstd[idx] = rs;
  xlast[idx] = (xp[(size_t)(L_ - 1) * DV_] - mu) * rs;
}

// ---------------------------------------------------------------------------
// Normalize + transpose: xnT[b,d,l] = (x[b,l,d]-mu[b,d])*rstd[b,d]  (bf16)
// ---------------------------------------------------------------------------
__global__ __launch_bounds__(256)
void tnorm_k(const float* __restrict__ x, const float* __restrict__ means,
             const float* __restrict__ rstd, short* __restrict__ xnT)
{
  __shared__ float tile[64][65];
  const int t = threadIdx.x;
  const int j = t & 63;
  const int i0 = t >> 6;                 // 0..3
  const int bz = blockIdx.z;
  const int l0 = blockIdx.y << 6;
  const int d0 = blockIdx.x << 6;
  const float* xp = x + ((size_t)bz * L_ + l0) * DV_ + d0;
  #pragma unroll
  for (int i = i0; i < 64; i += 4) tile[i][j] = xp[(size_t)i * DV_ + j];
  __syncthreads();
  short* op = xnT + ((size_t)bz * DV_ + d0) * L_ + l0;
  const int sb = bz * DV_ + d0;
  #pragma unroll
  for (int i = i0; i < 64; i += 4) {
    float mu = means[sb + i];
    float rs = rstd[sb + i];
    op[(size_t)i * L_ + j] = f2bf((tile[j][i] - mu) * rs);
  }
}

// ---------------------------------------------------------------------------
// LayerNorm over last dim (512) of fp32 h -> bf16 out.  One block per row.
// ---------------------------------------------------------------------------
__global__ __launch_bounds__(256)
void ln_k(const float* __restrict__ X, const float* __restrict__ g,
          const float* __restrict__ b, short* __restrict__ Y)
{
  int row = blockIdx.x;
  const float* x = X + (size_t)row * DM_;
  int t = threadIdx.x;
  float v0 = x[t], v1 = x[t + 256];
  float s = v0 + v1, ss = v0 * v0 + v1 * v1;
  #pragma unroll
  for (int o = 1; o < 64; o <<= 1) { s += __shfl_xor(s, o); ss += __shfl_xor(ss, o); }
  __shared__ float sb[8];
  int wave = t >> 6, lane = t & 63;
  if (lane == 0) { sb[wave] = s; sb[4 + wave] = ss; }
  __syncthreads();
  s = sb[0] + sb[1] + sb[2] + sb[3];
  ss = sb[4] + sb[5] + sb[6] + sb[7];
  float mu = s / (float)DM_;
  float var = ss / (float)DM_ - mu * mu;
  float rs = rsqrtf(var + 1e-5f);
  Y[(size_t)row * DM_ + t]       = f2bf((v0 - mu) * rs * g[t]       + b[t]);
  Y[(size_t)row * DM_ + t + 256] = f2bf((v1 - mu) * rs * g[t + 256] + b[t + 256]);
}

// ---------------------------------------------------------------------------
// Depthwise causal conv (DC=4 taps) + bias + silu.  REV templated.
// ---------------------------------------------------------------------------
template <int REV>
__global__ __launch_bounds__(256)
void conv_k(const short* __restrict__ xz, const float* __restrict__ w,
            const float* __restrict__ cb, short* __restrict__ xc)
{
  int idx = blockIdx.x * 256 + threadIdx.x;   // over B*S*DI
  int i = idx & (DI_ - 1);
  int bs = idx >> 10;                         // b*S + t
  int tt0 = bs & (S_ - 1);
  int b = bs >> 9;
  const short* u = xz + (size_t)b * S_ * (2 * DI_) + i;   // row stride 2*DI
  float acc = cb[i];
  #pragma unroll
  for (int k = 0; k < DC_; k++) {
    int tt = REV ? (tt0 + (DC_ - 1) - k) : (tt0 - (DC_ - 1) + k);
    if (tt >= 0 && tt < S_)
      acc += w[i * DC_ + k] * bf2f(u[(size_t)tt * (2 * DI_)]);
  }
  float sig = 1.f / (1.f + __expf(-acc));
  xc[idx] = f2bf(acc * sig);
}

// ---------------------------------------------------------------------------
// Chunked selective scan, thread owns (b,i,chunk) with all 16 n-states in
// registers.  P1: local scan from 0, store chunk state + prod(dA) (fp16).
// P2: inter-chunk combine (part_h[c] becomes chunk c's incoming state).
// P3: recompute with incoming state, emit y = (sum_n h*C + u*D)*silu(z).
// part layout: [((c*B + b)*DI + i)*16 + n]  fp16
// ---------------------------------------------------------------------------
template <int REV>
__global__ __launch_bounds__(256)
void scan_p1(const unsigned short* __restrict__ dt16, const short* __restrict__ xc,
             const short* __restrict__ xdbl, const float* __restrict__ A_log,
             unsigned short* __restrict__ part_h, unsigned short* __restrict__ part_A)
{
  const int g = blockIdx.x * 256 + threadIdx.x;   // b*DI + i
  const int b = g >> 10, i = g & (DI_ - 1);
  const int c = blockIdx.y;
  float Ai[16];
  const float* al = A_log + i * DS_;
  #pragma unroll
  for (int n = 0; n < 16; n++) Ai[n] = -__expf(al[n]);

  const int ti0 = REV ? (S_ - 1 - c * CS_) : (c * CS_);
  const unsigned short* pdt = dt16 + ((size_t)b * S_ + ti0) * DI_ + i;
  const short* pu = xc + ((size_t)b * S_ + ti0) * DI_ + i;
  const short* pbc = xdbl + (((size_t)b * S_ + ti0) << 6) + DTR_;
  const int sdt = REV ? -DI_ : DI_;
  const int sbc = REV ? -64 : 64;

  float h[16], pA[16];
  #pragma unroll
  for (int n = 0; n < 16; n++) { h[n] = 0.f; pA[n] = 1.f; }

  #pragma unroll 4
  for (int sl = 0; sl < CS_; sl++) {
    float dtv = h2f(*pdt);
    float u = bf2f(*pu);
    bf16x8 vB0 = ((const bf16x8*)pbc)[0];
    bf16x8 vB1 = ((const bf16x8*)pbc)[1];
    float du = dtv * u;
    #pragma unroll
    for (int n = 0; n < 8; n++) {
      float dA = __expf(dtv * Ai[n]);
      h[n] = dA * h[n] + du * bf2f(vB0[n]);
      pA[n] *= dA;
    }
    #pragma unroll
    for (int n = 0; n < 8; n++) {
      float dA = __expf(dtv * Ai[8 + n]);
      h[8 + n] = dA * h[8 + n] + du * bf2f(vB1[n]);
      pA[8 + n] *= dA;
    }
    pdt += sdt; pu += sdt; pbc += sbc;
  }
  unsigned short hv[16], av[16];
  #pragma unroll
  for (int n = 0; n < 16; n++) { hv[n] = f2h(h[n]); av[n] = f2h(pA[n]); }
  const size_t ix = (((size_t)c * B_ + b) * DI_ + i) << 4;
  #pragma unroll
  for (int q = 0; q < 2; q++) {
    ((int4*)(part_h + ix))[q] = ((const int4*)hv)[q];
    ((int4*)(part_A + ix))[q] = ((const int4*)av)[q];
  }
}

__global__ __launch_bounds__(256)
void scan_p2(unsigned short* __restrict__ part_h,
             const unsigned short* __restrict__ part_A)
{
  const size_t gid = (size_t)blockIdx.x * 256 + threadIdx.x;   // B*DI*DS
  const size_t stride = (size_t)B_ * DI_ * DS_;
  float hin = 0.f;
  #pragma unroll
  for (int c = 0; c < CH_; c++) {
    size_t ix = (size_t)c * stride + gid;
    float hh = h2f(part_h[ix]);
    float pA = h2f(part_A[ix]);
    part_h[ix] = f2h(hin);            // becomes chunk c's incoming state
    hin = hh + pA * hin;
  }
}

template <int REV>
__global__ __launch_bounds__(256)
void scan_p3(const unsigned short* __restrict__ dt16, const short* __restrict__ xc,
             const short* __restrict__ xdbl, const short* __restrict__ xz,
             const float* __restrict__ A_log, const float* __restrict__ Dp,
             const unsigned short* __restrict__ part_h, short* __restrict__ y)
{
  const int g = blockIdx.x * 256 + threadIdx.x;   // b*DI + i
  const int b = g >> 10, i = g & (DI_ - 1);
  const int c = blockIdx.y;
  float Ai[16];
  const float* al = A_log + i * DS_;
  #pragma unroll
  for (int n = 0; n < 16; n++) Ai[n] = -__expf(al[n]);
  const float Di = Dp[i];

  float h[16];
  {
    const size_t ix = (((size_t)c * B_ + b) * DI_ + i) << 4;
    unsigned short hv[16];
    ((int4*)hv)[0] = ((const int4*)(part_h + ix))[0];
    ((int4*)hv)[1] = ((const int4*)(part_h + ix))[1];
    #pragma unroll
    for (int n = 0; n < 16; n++) h[n] = h2f(hv[n]);
  }

  const int ti0 = REV ? (S_ - 1 - c * CS_) : (c * CS_);
  const unsigned short* pdt = dt16 + ((size_t)b * S_ + ti0) * DI_ + i;
  const short* pu = xc + ((size_t)b * S_ + ti0) * DI_ + i;
  const short* pbc = xdbl + (((size_t)b * S_ + ti0) << 6) + DTR_;
  const short* pz = xz + ((size_t)b * S_ + ti0) * (2 * DI_) + DI_ + i;
  short* py = y + ((size_t)b * S_ + ti0) * DI_ + i;
  const int sdt = REV ? -DI_ : DI_;
  const int sbc = REV ? -64 : 64;
  const int sz = REV ? -(2 * DI_) : (2 * DI_);

  #pragma unroll 4
  for (int sl = 0; sl < CS_; sl++) {
    float dtv = h2f(*pdt);
    float u = bf2f(*pu);
    bf16x8 vB0 = ((const bf16x8*)pbc)[0];
    bf16x8 vB1 = ((const bf16x8*)pbc)[1];
    bf16x8 vC0 = ((const bf16x8*)pbc)[2];
    bf16x8 vC1 = ((const bf16x8*)pbc)[3];
    float zv = bf2f(*pz);
    float du = dtv * u;
    float yp = 0.f;
    #pragma unroll
    for (int n = 0; n < 8; n++) {
      float dA = __expf(dtv * Ai[n]);
      h[n] = dA * h[n] + du * bf2f(vB0[n]);
      yp += h[n] * bf2f(vC0[n]);
    }
    #pragma unroll
    for (int n = 0; n < 8; n++) {
      float dA = __expf(dtv * Ai[8 + n]);
      h[8 + n] = dA * h[8 + n] + du * bf2f(vB1[n]);
      yp += h[8 + n] * bf2f(vC1[n]);
    }
    float sil = zv / (1.f + __expf(-zv));
    *py = f2bf((yp + u * Di) * sil);
    pdt += sdt; pu += sdt; pbc += sbc; pz += sz; py += sdt;
  }
}

// ---------------------------------------------------------------------------
// bf16 MFMA GEMM: C[M,N] = A[M,K] * W[N,K]^T, fp32 accum.  A bf16 internal
// (staged via global_load_lds width=16); W fp32 input converted during LDS
// staging with packed cvt.  128x128 tile, BK=32, 4 waves (2x2).
// ---------------------------------------------------------------------------
enum { EPI_F32_BIAS, EPI_BF16, EPI_F16_SOFTPLUS, EPI_ADD_HALF, EPI_GELU,
       EPI_ADD_BIAS, EPI_PROJ };

__device__ __forceinline__ bf16x8 cvt8(float4 a, float4 b) {
  union { bf16x8 v; __hip_bfloat162 h[4]; } u;
  u.h[0] = __float22bfloat162_rn(float2{a.x, a.y});
  u.h[1] = __float22bfloat162_rn(float2{a.z, a.w});
  u.h[2] = __float22bfloat162_rn(float2{b.x, b.y});
  u.h[3] = __float22bfloat162_rn(float2{b.z, b.w});
  return u.v;
}

template <int EPI>
__global__ __launch_bounds__(256)
void gemm_k(const short* __restrict__ A, const float* __restrict__ W,
            int N, int K, int lda, int ldw,
            float* __restrict__ Cf, short* __restrict__ Cb, int ldc,
            const float* __restrict__ bias,
            const float* __restrict__ xlast, const float* __restrict__ stdev,
            const float* __restrict__ means)
{
  __shared__ __align__(16) short As[128 * 32];
  __shared__ __align__(16) short Ws[128 * 32];
  const int tid = threadIdx.x;
  const int m0 = blockIdx.y * 128;
  const int n0 = blockIdx.x * 128;
  const int wave = tid >> 6, lane = tid & 63;
  const int wm = (wave & 1) << 6, wn = (wave >> 1) << 6;
  const int quad = lane >> 4, l16 = lane & 15;
  const int sr = tid >> 2;            // staging row 0..63
  const int sc = (tid & 3) << 3;      // staging k-offset (elements)

  f32x4 acc[4][4] = {};

  int wr0 = n0 + sr;      if (wr0 > N - 1) wr0 = N - 1;
  int wr1 = n0 + sr + 64; if (wr1 > N - 1) wr1 = N - 1;
  const size_t wrow0 = (size_t)wr0 * ldw + sc;
  const size_t wrow1 = (size_t)wr1 * ldw + sc;
  const short* gA0 = A + (size_t)(m0 + sr) * lda + sc;
  const short* gA1 = A + (size_t)(m0 + 64 + sr) * lda + sc;
  short* lA0 = As + wave * 512;           // 64 lanes x 16B per wave
  short* lA1 = As + 2048 + wave * 512;

  for (int k0 = 0; k0 < K; k0 += 32) {
    float4 w00 = *(const float4*)(W + wrow0 + k0);
    float4 w01 = *(const float4*)(W + wrow0 + k0 + 4);
    float4 w10 = *(const float4*)(W + wrow1 + k0);
    float4 w11 = *(const float4*)(W + wrow1 + k0 + 4);
    __syncthreads();
    load_lds16(gA0 + k0, lA0);
    load_lds16(gA1 + k0, lA1);
    *(bf16x8*)(Ws + sr * 32 + sc) = cvt8(w00, w01);
    *(bf16x8*)(Ws + (sr + 64) * 32 + sc) = cvt8(w10, w11);
    __syncthreads();
    bf16x8 af[4], bfr[4];
    #pragma unroll
    for (int mt = 0; mt < 4; mt++)
      af[mt] = *(const bf16x8*)(As + (wm + mt * 16 + l16) * 32 + (quad << 3));
    #pragma unroll
    for (int nt = 0; nt < 4; nt++)
      bfr[nt] = *(const bf16x8*)(Ws + (wn + nt * 16 + l16) * 32 + (quad << 3));
    #pragma unroll
    for (int mt = 0; mt < 4; mt++)
      #pragma unroll
      for (int nt = 0; nt < 4; nt++)
        acc[mt][nt] = __builtin_amdgcn_mfma_f32_16x16x32_bf16(af[mt], bfr[nt], acc[mt][nt], 0, 0, 0);
  }

  #pragma unroll
  for (int mt = 0; mt < 4; mt++) {
    #pragma unroll
    for (int nt = 0; nt < 4; nt++) {
      int n = n0 + wn + nt * 16 + l16;
      if (n >= N) continue;
      #pragma unroll
      for (int r = 0; r < 4; r++) {
        int m = m0 + wm + mt * 16 + quad * 4 + r;
        float v = acc[mt][nt][r];
        if constexpr (EPI == EPI_F32_BIAS) {
          Cf[(size_t)m * ldc + n] = v + bias[n];
        } else if constexpr (EPI == EPI_BF16) {
          Cb[(size_t)m * ldc + n] = f2bf(v);
        } else if constexpr (EPI == EPI_F16_SOFTPLUS) {
          float tt = v + bias[n];
          float sp = (tt > 20.f) ? tt : log1pf(__expf(tt));
          ((unsigned short*)Cb)[(size_t)m * ldc + n] = f2h(sp);
        } else if constexpr (EPI == EPI_ADD_HALF) {
          Cf[(size_t)m * ldc + n] += 0.5f * v;
        } else if constexpr (EPI == EPI_GELU) {
          float tt = v + bias[n];
          Cb[(size_t)m * ldc + n] = f2bf(0.5f * tt * (1.f + erff(tt * 0.70710678118f)));
        } else if constexpr (EPI == EPI_ADD_BIAS) {
          Cf[(size_t)m * ldc + n] += v + bias[n];
        } else if constexpr (EPI == EPI_PROJ) {
          int bb = m >> 9, d = m & 511;
          float tt = v + bias[n] + xlast[m];
          tt = tt * stdev[m] + means[m];
          Cf[((size_t)bb * PL_ + n) * DV_ + d] = tt;
        }
      }
    }
  }
}

// ---------------------------------------------------------------------------
extern "C" void kernel_launch(void* const* d_in, const int* in_sizes, int n_in,
                              void* d_out, int out_size, void* d_ws, size_t ws_size,
                              hipStream_t stream)
{
  (void)in_sizes; (void)n_in; (void)out_size; (void)ws_size;
  const float* x        = (const float*)d_in[0];
  const float* emb_w    = (const float*)d_in[1];
  const float* emb_b    = (const float*)d_in[2];
  const float* ln_g     = (const float*)d_in[3];
  const float* ln_b     = (const float*)d_in[4];
  const float* m_in_w   = (const float*)d_in[5];
  const float* m_conv_w = (const float*)d_in[6];
  const float* m_conv_b = (const float*)d_in[7];
  const float* m_xp_w   = (const float*)d_in[8];
  const float* m_dt_w   = (const float*)d_in[9];
  const float* m_dt_b   = (const float*)d_in[10];
  const float* m_A_log  = (const float*)d_in[11];
  const float* m_D      = (const float*)d_in[12];
  const float* m_out_w  = (const float*)d_in[13];
  const float* ffn_ln_g = (const float*)d_in[14];
  const float* ffn_ln_b = (const float*)d_in[15];
  const float* ffn_w1   = (const float*)d_in[16];
  const float* ffn_b1   = (const float*)d_in[17];
  const float* ffn_w2   = (const float*)d_in[18];
  const float* ffn_b2   = (const float*)d_in[19];
  const float* enc_g    = (const float*)d_in[20];
  const float* enc_b    = (const float*)d_in[21];
  const float* proj_w   = (const float*)d_in[22];
  const float* proj_b   = (const float*)d_in[23];
  float* out = (float*)d_out;

  char* ws = (char*)d_ws;
  const size_t MB = 1024 * 1024;
  float* h      = (float*)(ws + 0);        //  8 MB  (4096 x 512 fp32)
  short* hn     = (short*)(ws + 8 * MB);   //  4 MB  (4096 x 512 bf16)
  short* xz     = (short*)(ws + 12 * MB);  // 16 MB  (4096 x 2048 bf16) also FFN hidden
  short* xc     = (short*)(ws + 28 * MB);  //  8 MB  (4096 x 1024 bf16)
  short* xdbl   = (short*)(ws + 36 * MB);  // .5 MB  (4096 x 64 bf16)
  unsigned short* dtb = (unsigned short*)(ws + 37 * MB); // 8 MB (4096 x 1024 fp16)
  unsigned short* part_h = (unsigned short*)(ws + 45 * MB); // 4 MB (16x8x1024x16 fp16)
  unsigned short* part_A = (unsigned short*)(ws + 49 * MB); // 4 MB
  short* yact   = (short*)(ws + 53 * MB);  //  8 MB  (4096 x 1024 bf16); xnT aliases
  short* xnT    = (short*)(ws + 53 * MB);  //  4 MB  pre-layer only
  float* stats  = (float*)(ws + 61 * MB);  // 64 KB
  float* means = stats, *stdevp = stats + 4096, *rstd = stats + 8192, *xlast = stats + 12288;

  dim3 blk(256);

  stats_k<<<dim3(2, B_), blk, 0, stream>>>(x, means, stdevp, rstd, xlast);
  tnorm_k<<<dim3(8, 8, B_), blk, 0, stream>>>(x, means, rstd, xnT);
  gemm_k<EPI_F32_BIAS><<<dim3(4, 32), blk, 0, stream>>>(
      xnT, emb_w, DM_, L_, L_, L_, h, nullptr, DM_, emb_b, nullptr, nullptr, nullptr);

  for (int il = 0; il < EL_; il++) {
    ln_k<<<dim3(4096), blk, 0, stream>>>(h, ln_g + il * DM_, ln_b + il * DM_, hn);
    for (int dir = 0; dir < 2; dir++) {
      int mod = 2 * il + dir;
      gemm_k<EPI_BF16><<<dim3(16, 32), blk, 0, stream>>>(
          hn, m_in_w + (size_t)mod * 2 * DI_ * DM_, 2 * DI_, DM_, DM_, DM_,
          nullptr, xz, 2 * DI_, nullptr, nullptr, nullptr, nullptr);
      if (dir == 0)
        conv_k<0><<<dim3(16384), blk, 0, stream>>>(
            xz, m_conv_w + (size_t)mod * DI_ * DC_, m_conv_b + (size_t)mod * DI_, xc);
      else
        conv_k<1><<<dim3(16384), blk, 0, stream>>>(
            xz, m_conv_w + (size_t)mod * DI_ * DC_, m_conv_b + (size_t)mod * DI_, xc);
      gemm_k<EPI_BF16><<<dim3(1, 32), blk, 0, stream>>>(
          xc, m_xp_w + (size_t)mod * (DTR_ + 2 * DS_) * DI_, DTR_ + 2 * DS_, DI_, DI_, DI_,
          nullptr, xdbl, DTR_ + 2 * DS_, nullptr, nullptr, nullptr, nullptr);
      gemm_k<EPI_F16_SOFTPLUS><<<dim3(8, 32), blk, 0, stream>>>(
          xdbl, m_dt_w + (size_t)mod * DI_ * DTR_, DI_, DTR_, DTR_ + 2 * DS_, DTR_,
          nullptr, (short*)dtb, DI_, m_dt_b + (size_t)mod * DI_, nullptr, nullptr, nullptr);
      const float* Alog = m_A_log + (size_t)mod * DI_ * DS_;
      const float* Dp = m_D + (size_t)mod * DI_;
      if (dir == 0) {
        scan_p1<0><<<dim3(32, CH_), blk, 0, stream>>>(dtb, xc, xdbl, Alog, part_h, part_A);
        scan_p2<<<dim3(512), blk, 0, stream>>>(part_h, part_A);
        scan_p3<0><<<dim3(32, CH_), blk, 0, stream>>>(dtb, xc, xdbl, xz, Alog, Dp, part_h, yact);
      } else {
        scan_p1<1><<<dim3(32, CH_), blk, 0, stream>>>(dtb, xc, xdbl, Alog, part_h, part_A);
        scan_p2<<<dim3(512), blk, 0, stream>>>(part_h, part_A);
        scan_p3<1><<<dim3(32, CH_), blk, 0, stream>>>(dtb, xc, xdbl, xz, Alog, Dp, part_h, yact);
      }
      gemm_k<EPI_ADD_HALF><<<dim3(4, 32), blk, 0, stream>>>(
          yact, m_out_w + (size_t)mod * DM_ * DI_, DM_, DI_, DI_, DI_,
          h, nullptr, DM_, nullptr, nullptr, nullptr, nullptr);
    }
    ln_k<<<dim3(4096), blk, 0, stream>>>(h, ffn_ln_g + il * DM_, ffn_ln_b + il * DM_, hn);
    gemm_k<EPI_GELU><<<dim3(16, 32), blk, 0, stream>>>(
        hn, ffn_w1 + (size_t)il * 4 * DM_ * DM_, 4 * DM_, DM_, DM_, DM_,
        nullptr, xz, 4 * DM_, ffn_b1 + (size_t)il * 4 * DM_, nullptr, nullptr, nullptr);
    gemm_k<EPI_ADD_BIAS><<<dim3(4, 32), blk, 0, stream>>>(
        xz, ffn_w2 + (size_t)il * DM_ * 4 * DM_, DM_, 4 * DM_, 4 * DM_, 4 * DM_,
        h, nullptr, DM_, ffn_b2 + (size_t)il * DM_, nullptr, nullptr, nullptr);
  }

  ln_k<<<dim3(4096), blk, 0, stream>>>(h, enc_g, enc_b, hn);
  gemm_k<EPI_PROJ><<<dim3(1, 32), blk, 0, stream>>>(
      hn, proj_w, PL_, DM_, DM_, DM_, out, nullptr, 0, proj_b, xlast, stdevp, means);
}

// Round 5
// 1692.718 us; speedup vs baseline: 1.4041x; 1.4041x over previous
//
#include <hip/hip_runtime.h>
#include <hip/hip_bf16.h>
#include <math.h>

#define B_ 8
#define L_ 512
#define DV_ 512
#define DM_ 512
#define PL_ 96
#define EL_ 3
#define DS_ 16
#define DC_ 4
#define DI_ 1024
#define DTR_ 32
#define S_ 512
#define CH_ 16         // scan chunks
#define CS_ 32         // steps per chunk

typedef float f32x4 __attribute__((ext_vector_type(4)));
typedef short bf16x8 __attribute__((ext_vector_type(8)));

__device__ __forceinline__ float bf2f(short s) {
  unsigned u = ((unsigned)(unsigned short)s) << 16;
  return __builtin_bit_cast(float, u);
}
__device__ __forceinline__ short f2bf(float f) {
  unsigned u = __builtin_bit_cast(unsigned, f);
  u = u + 0x7FFFu + ((u >> 16) & 1u);   // RNE
  return (short)(u >> 16);
}
__device__ __forceinline__ float h2f(unsigned short u) {
  _Float16 h = __builtin_bit_cast(_Float16, u);
  return (float)h;
}
__device__ __forceinline__ unsigned short f2h(float f) {
  _Float16 h = (_Float16)f;
  return __builtin_bit_cast(unsigned short, h);
}

// ---------------------------------------------------------------------------
// Instance-norm statistics over the time axis (L) of x (B,L,DV) fp32.
// ---------------------------------------------------------------------------
__global__ __launch_bounds__(256)
void stats_k(const float* __restrict__ x, float* __restrict__ means,
             float* __restrict__ stdev, float* __restrict__ rstd,
             float* __restrict__ xlast)
{
  int d = blockIdx.x * 256 + threadIdx.x;       // 0..511
  int b = blockIdx.y;
  const float* xp = x + (size_t)b * L_ * DV_ + d;
  float s = 0.f, ss = 0.f;
  for (int l = 0; l < L_; l++) {
    float v = xp[(size_t)l * DV_];
    s += v; ss += v * v;
  }
  float mu = s / (float)L_;
  float var = ss / (float)L_ - mu * mu;
  float sd = sqrtf(var + 1e-5f);
  float rs = 1.f / sd;
  int idx = b * DV_ + d;
  means[idx] = mu; stdev[idx] = sd; rstd[idx] = rs;
  xlast[idx] = (xp[(size_t)(L_ - 1) * DV_] - mu) * rs;
}

// ---------------------------------------------------------------------------
// Normalize + transpose: xnT[b,d,l] = (x[b,l,d]-mu[b,d])*rstd[b,d]  (bf16)
// ---------------------------------------------------------------------------
__global__ __launch_bounds__(256)
void tnorm_k(const float* __restrict__ x, const float* __restrict__ means,
             const float* __restrict__ rstd, short* __restrict__ xnT)
{
  __shared__ float tile[64][65];
  const int t = threadIdx.x;
  const int j = t & 63;
  const int i0 = t >> 6;                 // 0..3
  const int bz = blockIdx.z;
  const int l0 = blockIdx.y << 6;
  const int d0 = blockIdx.x << 6;
  const float* xp = x + ((size_t)bz * L_ + l0) * DV_ + d0;
  #pragma unroll
  for (int i = i0; i < 64; i += 4) tile[i][j] = xp[(size_t)i * DV_ + j];
  __syncthreads();
  short* op = xnT + ((size_t)bz * DV_ + d0) * L_ + l0;
  const int sb = bz * DV_ + d0;
  #pragma unroll
  for (int i = i0; i < 64; i += 4) {
    float mu = means[sb + i];
    float rs = rstd[sb + i];
    op[(size_t)i * L_ + j] = f2bf((tile[j][i] - mu) * rs);
  }
}

// ---------------------------------------------------------------------------
// LayerNorm over last dim (512) of fp32 h -> bf16 out.  One block per row.
// ---------------------------------------------------------------------------
__global__ __launch_bounds__(256)
void ln_k(const float* __restrict__ X, const float* __restrict__ g,
          const float* __restrict__ b, short* __restrict__ Y)
{
  int row = blockIdx.x;
  const float* x = X + (size_t)row * DM_;
  int t = threadIdx.x;
  float v0 = x[t], v1 = x[t + 256];
  float s = v0 + v1, ss = v0 * v0 + v1 * v1;
  #pragma unroll
  for (int o = 1; o < 64; o <<= 1) { s += __shfl_xor(s, o); ss += __shfl_xor(ss, o); }
  __shared__ float sb[8];
  int wave = t >> 6, lane = t & 63;
  if (lane == 0) { sb[wave] = s; sb[4 + wave] = ss; }
  __syncthreads();
  s = sb[0] + sb[1] + sb[2] + sb[3];
  ss = sb[4] + sb[5] + sb[6] + sb[7];
  float mu = s / (float)DM_;
  float var = ss / (float)DM_ - mu * mu;
  float rs = rsqrtf(var + 1e-5f);
  Y[(size_t)row * DM_ + t]       = f2bf((v0 - mu) * rs * g[t]       + b[t]);
  Y[(size_t)row * DM_ + t + 256] = f2bf((v1 - mu) * rs * g[t + 256] + b[t + 256]);
}

// ---------------------------------------------------------------------------
// Depthwise causal conv (DC=4 taps) + bias + silu.  REV templated.
// ---------------------------------------------------------------------------
template <int REV>
__global__ __launch_bounds__(256)
void conv_k(const short* __restrict__ xz, const float* __restrict__ w,
            const float* __restrict__ cb, short* __restrict__ xc)
{
  int idx = blockIdx.x * 256 + threadIdx.x;   // over B*S*DI
  int i = idx & (DI_ - 1);
  int bs = idx >> 10;                         // b*S + t
  int tt0 = bs & (S_ - 1);
  int b = bs >> 9;
  const short* u = xz + (size_t)b * S_ * (2 * DI_) + i;   // row stride 2*DI
  float acc = cb[i];
  #pragma unroll
  for (int k = 0; k < DC_; k++) {
    int tt = REV ? (tt0 + (DC_ - 1) - k) : (tt0 - (DC_ - 1) + k);
    if (tt >= 0 && tt < S_)
      acc += w[i * DC_ + k] * bf2f(u[(size_t)tt * (2 * DI_)]);
  }
  float sig = 1.f / (1.f + __expf(-acc));
  xc[idx] = f2bf(acc * sig);
}

// ---------------------------------------------------------------------------
// Chunked selective scan, thread owns (b,i,chunk) with all 16 n-states in
// registers.  P1: local scan from 0, store chunk state + prod(dA) (fp16).
// P2: inter-chunk combine.  P3: recompute with incoming state, emit
// y = (sum_n h*C + u*D)*silu(z).   part layout: [((c*B+b)*DI+i)*16+n] fp16
// ---------------------------------------------------------------------------
template <int REV>
__global__ __launch_bounds__(256)
void scan_p1(const unsigned short* __restrict__ dt16, const short* __restrict__ xc,
             const short* __restrict__ xdbl, const float* __restrict__ A_log,
             unsigned short* __restrict__ part_h, unsigned short* __restrict__ part_A)
{
  const int g = blockIdx.x * 256 + threadIdx.x;   // b*DI + i
  const int b = g >> 10, i = g & (DI_ - 1);
  const int c = blockIdx.y;
  float Ai[16];
  const float* al = A_log + i * DS_;
  #pragma unroll
  for (int n = 0; n < 16; n++) Ai[n] = -__expf(al[n]);

  const int ti0 = REV ? (S_ - 1 - c * CS_) : (c * CS_);
  const unsigned short* pdt = dt16 + ((size_t)b * S_ + ti0) * DI_ + i;
  const short* pu = xc + ((size_t)b * S_ + ti0) * DI_ + i;
  const short* pbc = xdbl + (((size_t)b * S_ + ti0) << 6) + DTR_;
  const int sdt = REV ? -DI_ : DI_;
  const int sbc = REV ? -64 : 64;

  float h[16], pA[16];
  #pragma unroll
  for (int n = 0; n < 16; n++) { h[n] = 0.f; pA[n] = 1.f; }

  #pragma unroll 4
  for (int sl = 0; sl < CS_; sl++) {
    float dtv = h2f(*pdt);
    float u = bf2f(*pu);
    bf16x8 vB0 = ((const bf16x8*)pbc)[0];
    bf16x8 vB1 = ((const bf16x8*)pbc)[1];
    float du = dtv * u;
    #pragma unroll
    for (int n = 0; n < 8; n++) {
      float dA = __expf(dtv * Ai[n]);
      h[n] = dA * h[n] + du * bf2f(vB0[n]);
      pA[n] *= dA;
    }
    #pragma unroll
    for (int n = 0; n < 8; n++) {
      float dA = __expf(dtv * Ai[8 + n]);
      h[8 + n] = dA * h[8 + n] + du * bf2f(vB1[n]);
      pA[8 + n] *= dA;
    }
    pdt += sdt; pu += sdt; pbc += sbc;
  }
  unsigned short hv[16], av[16];
  #pragma unroll
  for (int n = 0; n < 16; n++) { hv[n] = f2h(h[n]); av[n] = f2h(pA[n]); }
  const size_t ix = (((size_t)c * B_ + b) * DI_ + i) << 4;
  #pragma unroll
  for (int q = 0; q < 2; q++) {
    ((int4*)(part_h + ix))[q] = ((const int4*)hv)[q];
    ((int4*)(part_A + ix))[q] = ((const int4*)av)[q];
  }
}

__global__ __launch_bounds__(256)
void scan_p2(unsigned short* __restrict__ part_h,
             const unsigned short* __restrict__ part_A)
{
  const size_t gid = (size_t)blockIdx.x * 256 + threadIdx.x;   // B*DI*DS
  const size_t stride = (size_t)B_ * DI_ * DS_;
  float hin = 0.f;
  #pragma unroll
  for (int c = 0; c < CH_; c++) {
    size_t ix = (size_t)c * stride + gid;
    float hh = h2f(part_h[ix]);
    float pA = h2f(part_A[ix]);
    part_h[ix] = f2h(hin);            // becomes chunk c's incoming state
    hin = hh + pA * hin;
  }
}

template <int REV>
__global__ __launch_bounds__(256)
void scan_p3(const unsigned short* __restrict__ dt16, const short* __restrict__ xc,
             const short* __restrict__ xdbl, const short* __restrict__ xz,
             const float* __restrict__ A_log, const float* __restrict__ Dp,
             const unsigned short* __restrict__ part_h, short* __restrict__ y)
{
  const int g = blockIdx.x * 256 + threadIdx.x;   // b*DI + i
  const int b = g >> 10, i = g & (DI_ - 1);
  const int c = blockIdx.y;
  float Ai[16];
  const float* al = A_log + i * DS_;
  #pragma unroll
  for (int n = 0; n < 16; n++) Ai[n] = -__expf(al[n]);
  const float Di = Dp[i];

  float h[16];
  {
    const size_t ix = (((size_t)c * B_ + b) * DI_ + i) << 4;
    unsigned short hv[16];
    ((int4*)hv)[0] = ((const int4*)(part_h + ix))[0];
    ((int4*)hv)[1] = ((const int4*)(part_h + ix))[1];
    #pragma unroll
    for (int n = 0; n < 16; n++) h[n] = h2f(hv[n]);
  }

  const int ti0 = REV ? (S_ - 1 - c * CS_) : (c * CS_);
  const unsigned short* pdt = dt16 + ((size_t)b * S_ + ti0) * DI_ + i;
  const short* pu = xc + ((size_t)b * S_ + ti0) * DI_ + i;
  const short* pbc = xdbl + (((size_t)b * S_ + ti0) << 6) + DTR_;
  const short* pz = xz + ((size_t)b * S_ + ti0) * (2 * DI_) + DI_ + i;
  short* py = y + ((size_t)b * S_ + ti0) * DI_ + i;
  const int sdt = REV ? -DI_ : DI_;
  const int sbc = REV ? -64 : 64;
  const int sz = REV ? -(2 * DI_) : (2 * DI_);

  #pragma unroll 4
  for (int sl = 0; sl < CS_; sl++) {
    float dtv = h2f(*pdt);
    float u = bf2f(*pu);
    bf16x8 vB0 = ((const bf16x8*)pbc)[0];
    bf16x8 vB1 = ((const bf16x8*)pbc)[1];
    bf16x8 vC0 = ((const bf16x8*)pbc)[2];
    bf16x8 vC1 = ((const bf16x8*)pbc)[3];
    float zv = bf2f(*pz);
    float du = dtv * u;
    float yp = 0.f;
    #pragma unroll
    for (int n = 0; n < 8; n++) {
      float dA = __expf(dtv * Ai[n]);
      h[n] = dA * h[n] + du * bf2f(vB0[n]);
      yp += h[n] * bf2f(vC0[n]);
    }
    #pragma unroll
    for (int n = 0; n < 8; n++) {
      float dA = __expf(dtv * Ai[8 + n]);
      h[8 + n] = dA * h[8 + n] + du * bf2f(vB1[n]);
      yp += h[8 + n] * bf2f(vC1[n]);
    }
    float sil = zv / (1.f + __expf(-zv));
    *py = f2bf((yp + u * Di) * sil);
    pdt += sdt; pu += sdt; pbc += sbc; pz += sz; py += sdt;
  }
}

// ---------------------------------------------------------------------------
// bf16 MFMA GEMM: C[M,N] = A[M,K] * W[N,K]^T, fp32 accum.
// Templated tile BM x BN (128 or 64), BK=32, 4 waves (2x2), each wave
// (BM/2)x(BN/2).  A staged via VGPR prefetch (loads for iter k+1 overlap
// MFMAs of iter k across the barrier — do NOT use global_load_lds here:
// direct-to-LDS cannot issue before the barrier and serializes the loop
// at low blocks/CU).  W is fp32, converted to bf16 during staging.
// ---------------------------------------------------------------------------
enum { EPI_F32_BIAS, EPI_BF16, EPI_F16_SOFTPLUS, EPI_ADD_HALF, EPI_GELU,
       EPI_ADD_BIAS, EPI_PROJ };

__device__ __forceinline__ bf16x8 cvt8(float4 a, float4 b) {
  union { bf16x8 v; __hip_bfloat162 h[4]; } u;
  u.h[0] = __float22bfloat162_rn(float2{a.x, a.y});
  u.h[1] = __float22bfloat162_rn(float2{a.z, a.w});
  u.h[2] = __float22bfloat162_rn(float2{b.x, b.y});
  u.h[3] = __float22bfloat162_rn(float2{b.z, b.w});
  return u.v;
}

template <int EPI, int BM, int BN>
__global__ __launch_bounds__(256)
void gemm_k(const short* __restrict__ A, const float* __restrict__ W,
            int N, int K, int lda, int ldw,
            float* __restrict__ Cf, short* __restrict__ Cb, int ldc,
            const float* __restrict__ bias,
            const float* __restrict__ xlast, const float* __restrict__ stdev,
            const float* __restrict__ means)
{
  constexpr int MT = BM / 32;         // MFMA tiles per wave (m)
  constexpr int NT = BN / 32;         // MFMA tiles per wave (n)
  constexpr int RM = BM / 64;         // staging rows per thread (A)
  constexpr int RN = BN / 64;         // staging rows per thread (W)
  __shared__ __align__(16) short As[BM * 32];
  __shared__ __align__(16) short Ws[BN * 32];
  const int tid = threadIdx.x;
  const int m0 = blockIdx.y * BM;
  const int n0 = blockIdx.x * BN;
  const int wave = tid >> 6, lane = tid & 63;
  const int wm = (wave & 1) * (BM / 2), wn = (wave >> 1) * (BN / 2);
  const int quad = lane >> 4, l16 = lane & 15;
  const int sr = tid >> 2;            // staging row 0..63
  const int sc = (tid & 3) << 3;      // staging k-offset (elements)

  f32x4 acc[MT][NT] = {};

  size_t arow[RM], wrow[RN];
  #pragma unroll
  for (int r = 0; r < RM; r++)
    arow[r] = (size_t)(m0 + r * 64 + sr) * lda + sc;
  #pragma unroll
  for (int r = 0; r < RN; r++) {
    int wr = n0 + r * 64 + sr; if (wr > N - 1) wr = N - 1;
    wrow[r] = (size_t)wr * ldw + sc;
  }

  for (int k0 = 0; k0 < K; k0 += 32) {
    int4 av[RM];
    float4 wv0[RN], wv1[RN];
    #pragma unroll
    for (int r = 0; r < RM; r++) av[r] = *(const int4*)(A + arow[r] + k0);
    #pragma unroll
    for (int r = 0; r < RN; r++) {
      wv0[r] = *(const float4*)(W + wrow[r] + k0);
      wv1[r] = *(const float4*)(W + wrow[r] + k0 + 4);
    }
    __syncthreads();
    #pragma unroll
    for (int r = 0; r < RM; r++)
      *(int4*)(As + (r * 64 + sr) * 32 + sc) = av[r];
    #pragma unroll
    for (int r = 0; r < RN; r++)
      *(bf16x8*)(Ws + (r * 64 + sr) * 32 + sc) = cvt8(wv0[r], wv1[r]);
    __syncthreads();
    bf16x8 af[MT], bfr[NT];
    #pragma unroll
    for (int mt = 0; mt < MT; mt++)
      af[mt] = *(const bf16x8*)(As + (wm + mt * 16 + l16) * 32 + (quad << 3));
    #pragma unroll
    for (int nt = 0; nt < NT; nt++)
      bfr[nt] = *(const bf16x8*)(Ws + (wn + nt * 16 + l16) * 32 + (quad << 3));
    #pragma unroll
    for (int mt = 0; mt < MT; mt++)
      #pragma unroll
      for (int nt = 0; nt < NT; nt++)
        acc[mt][nt] = __builtin_amdgcn_mfma_f32_16x16x32_bf16(af[mt], bfr[nt], acc[mt][nt], 0, 0, 0);
  }

  #pragma unroll
  for (int mt = 0; mt < MT; mt++) {
    #pragma unroll
    for (int nt = 0; nt < NT; nt++) {
      int n = n0 + wn + nt * 16 + l16;
      if (n >= N) continue;
      #pragma unroll
      for (int r = 0; r < 4; r++) {
        int m = m0 + wm + mt * 16 + quad * 4 + r;
        float v = acc[mt][nt][r];
        if constexpr (EPI == EPI_F32_BIAS) {
          Cf[(size_t)m * ldc + n] = v + bias[n];
        } else if constexpr (EPI == EPI_BF16) {
          Cb[(size_t)m * ldc + n] = f2bf(v);
        } else if constexpr (EPI == EPI_F16_SOFTPLUS) {
          float tt = v + bias[n];
          float sp = (tt > 20.f) ? tt : log1pf(__expf(tt));
          ((unsigned short*)Cb)[(size_t)m * ldc + n] = f2h(sp);
        } else if constexpr (EPI == EPI_ADD_HALF) {
          Cf[(size_t)m * ldc + n] += 0.5f * v;
        } else if constexpr (EPI == EPI_GELU) {
          float tt = v + bias[n];
          Cb[(size_t)m * ldc + n] = f2bf(0.5f * tt * (1.f + erff(tt * 0.70710678118f)));
        } else if constexpr (EPI == EPI_ADD_BIAS) {
          Cf[(size_t)m * ldc + n] += v + bias[n];
        } else if constexpr (EPI == EPI_PROJ) {
          int bb = m >> 9, d = m & 511;
          float tt = v + bias[n] + xlast[m];
          tt = tt * stdev[m] + means[m];
          Cf[((size_t)bb * PL_ + n) * DV_ + d] = tt;
        }
      }
    }
  }
}

// ---------------------------------------------------------------------------
extern "C" void kernel_launch(void* const* d_in, const int* in_sizes, int n_in,
                              void* d_out, int out_size, void* d_ws, size_t ws_size,
                              hipStream_t stream)
{
  (void)in_sizes; (void)n_in; (void)out_size; (void)ws_size;
  const float* x        = (const float*)d_in[0];
  const float* emb_w    = (const float*)d_in[1];
  const float* emb_b    = (const float*)d_in[2];
  const float* ln_g     = (const float*)d_in[3];
  const float* ln_b     = (const float*)d_in[4];
  const float* m_in_w   = (const float*)d_in[5];
  const float* m_conv_w = (const float*)d_in[6];
  const float* m_conv_b = (const float*)d_in[7];
  const float* m_xp_w   = (const float*)d_in[8];
  const float* m_dt_w   = (const float*)d_in[9];
  const float* m_dt_b   = (const float*)d_in[10];
  const float* m_A_log  = (const float*)d_in[11];
  const float* m_D      = (const float*)d_in[12];
  const float* m_out_w  = (const float*)d_in[13];
  const float* ffn_ln_g = (const float*)d_in[14];
  const float* ffn_ln_b = (const float*)d_in[15];
  const float* ffn_w1   = (const float*)d_in[16];
  const float* ffn_b1   = (const float*)d_in[17];
  const float* ffn_w2   = (const float*)d_in[18];
  const float* ffn_b2   = (const float*)d_in[19];
  const float* enc_g    = (const float*)d_in[20];
  const float* enc_b    = (const float*)d_in[21];
  const float* proj_w   = (const float*)d_in[22];
  const float* proj_b   = (const float*)d_in[23];
  float* out = (float*)d_out;

  char* ws = (char*)d_ws;
  const size_t MB = 1024 * 1024;
  float* h      = (float*)(ws + 0);        //  8 MB  (4096 x 512 fp32)
  short* hn     = (short*)(ws + 8 * MB);   //  4 MB  (4096 x 512 bf16)
  short* xz     = (short*)(ws + 12 * MB);  // 16 MB  (4096 x 2048 bf16) also FFN hidden
  short* xc     = (short*)(ws + 28 * MB);  //  8 MB  (4096 x 1024 bf16)
  short* xdbl   = (short*)(ws + 36 * MB);  // .5 MB  (4096 x 64 bf16)
  unsigned short* dtb = (unsigned short*)(ws + 37 * MB); // 8 MB (4096 x 1024 fp16)
  unsigned short* part_h = (unsigned short*)(ws + 45 * MB); // 4 MB (16x8x1024x16 fp16)
  unsigned short* part_A = (unsigned short*)(ws + 49 * MB); // 4 MB
  short* yact   = (short*)(ws + 53 * MB);  //  8 MB  (4096 x 1024 bf16); xnT aliases
  short* xnT    = (short*)(ws + 53 * MB);  //  4 MB  pre-layer only
  float* stats  = (float*)(ws + 61 * MB);  // 64 KB
  float* means = stats, *stdevp = stats + 4096, *rstd = stats + 8192, *xlast = stats + 12288;

  dim3 blk(256);

  stats_k<<<dim3(2, B_), blk, 0, stream>>>(x, means, stdevp, rstd, xlast);
  tnorm_k<<<dim3(8, 8, B_), blk, 0, stream>>>(x, means, rstd, xnT);
  // emb: M=4096, N=512, K=512 — 64x64 tiles, 512 blocks
  gemm_k<EPI_F32_BIAS, 64, 64><<<dim3(8, 64), blk, 0, stream>>>(
      xnT, emb_w, DM_, L_, L_, L_, h, nullptr, DM_, emb_b, nullptr, nullptr, nullptr);

  for (int il = 0; il < EL_; il++) {
    ln_k<<<dim3(4096), blk, 0, stream>>>(h, ln_g + il * DM_, ln_b + il * DM_, hn);
    for (int dir = 0; dir < 2; dir++) {
      int mod = 2 * il + dir;
      // in-proj: N=2048, K=512 — 128x128 tiles, 512 blocks
      gemm_k<EPI_BF16, 128, 128><<<dim3(16, 32), blk, 0, stream>>>(
          hn, m_in_w + (size_t)mod * 2 * DI_ * DM_, 2 * DI_, DM_, DM_, DM_,
          nullptr, xz, 2 * DI_, nullptr, nullptr, nullptr, nullptr);
      if (dir == 0)
        conv_k<0><<<dim3(16384), blk, 0, stream>>>(
            xz, m_conv_w + (size_t)mod * DI_ * DC_, m_conv_b + (size_t)mod * DI_, xc);
      else
        conv_k<1><<<dim3(16384), blk, 0, stream>>>(
            xz, m_conv_w + (size_t)mod * DI_ * DC_, m_conv_b + (size_t)mod * DI_, xc);
      // xdbl: N=64, K=1024 — 64x64 tiles, 64 blocks
      gemm_k<EPI_BF16, 64, 64><<<dim3(1, 64), blk, 0, stream>>>(
          xc, m_xp_w + (size_t)mod * (DTR_ + 2 * DS_) * DI_, DTR_ + 2 * DS_, DI_, DI_, DI_,
          nullptr, xdbl, DTR_ + 2 * DS_, nullptr, nullptr, nullptr, nullptr);
      // dt: N=1024, K=32 — 64x64 tiles, 1024 blocks
      gemm_k<EPI_F16_SOFTPLUS, 64, 64><<<dim3(16, 64), blk, 0, stream>>>(
          xdbl, m_dt_w + (size_t)mod * DI_ * DTR_, DI_, DTR_, DTR_ + 2 * DS_, DTR_,
          nullptr, (short*)dtb, DI_, m_dt_b + (size_t)mod * DI_, nullptr, nullptr, nullptr);
      const float* Alog = m_A_log + (size_t)mod * DI_ * DS_;
      const float* Dp = m_D + (size_t)mod * DI_;
      if (dir == 0) {
        scan_p1<0><<<dim3(32, CH_), blk, 0, stream>>>(dtb, xc, xdbl, Alog, part_h, part_A);
        scan_p2<<<dim3(512), blk, 0, stream>>>(part_h, part_A);
        scan_p3<0><<<dim3(32, CH_), blk, 0, stream>>>(dtb, xc, xdbl, xz, Alog, Dp, part_h, yact);
      } else {
        scan_p1<1><<<dim3(32, CH_), blk, 0, stream>>>(dtb, xc, xdbl, Alog, part_h, part_A);
        scan_p2<<<dim3(512), blk, 0, stream>>>(part_h, part_A);
        scan_p3<1><<<dim3(32, CH_), blk, 0, stream>>>(dtb, xc, xdbl, xz, Alog, Dp, part_h, yact);
      }
      // out-proj: N=512, K=1024 — 64x64 tiles, 512 blocks
      gemm_k<EPI_ADD_HALF, 64, 64><<<dim3(8, 64), blk, 0, stream>>>(
          yact, m_out_w + (size_t)mod * DM_ * DI_, DM_, DI_, DI_, DI_,
          h, nullptr, DM_, nullptr, nullptr, nullptr, nullptr);
    }
    ln_k<<<dim3(4096), blk, 0, stream>>>(h, ffn_ln_g + il * DM_, ffn_ln_b + il * DM_, hn);
    // ffn1: N=2048, K=512 — 128x128 tiles, 512 blocks
    gemm_k<EPI_GELU, 128, 128><<<dim3(16, 32), blk, 0, stream>>>(
        hn, ffn_w1 + (size_t)il * 4 * DM_ * DM_, 4 * DM_, DM_, DM_, DM_,
        nullptr, xz, 4 * DM_, ffn_b1 + (size_t)il * 4 * DM_, nullptr, nullptr, nullptr);
    // ffn2: N=512, K=2048 — 64x64 tiles, 512 blocks
    gemm_k<EPI_ADD_BIAS, 64, 64><<<dim3(8, 64), blk, 0, stream>>>(
        xz, ffn_w2 + (size_t)il * DM_ * 4 * DM_, DM_, 4 * DM_, 4 * DM_, 4 * DM_,
        h, nullptr, DM_, ffn_b2 + (size_t)il * DM_, nullptr, nullptr, nullptr);
  }

  ln_k<<<dim3(4096), blk, 0, stream>>>(h, enc_g, enc_b, hn);
  // proj: N=96, K=512 — 64x64 tiles, 128 blocks
  gemm_k<EPI_PROJ, 64, 64><<<dim3(2, 64), blk, 0, stream>>>(
      hn, proj_w, PL_, DM_, DM_, DM_, out, nullptr, 0, proj_b, xlast, stdevp, means);
}